// Round 10
// baseline (274.499 us; speedup 1.0000x reference)
//
#include <hip/hip_runtime.h>
#include <hip/hip_bf16.h>
#include <hip/hip_fp16.h>

typedef unsigned short u16;
typedef __attribute__((ext_vector_type(8))) _Float16 f16x8;   // 8 fp16 = 4 VGPR
typedef __attribute__((ext_vector_type(16))) float f32x16;    // MFMA 32x32 acc

#define B_ 8
#define S_ 2048
#define H_ 1024
#define M_ (B_ * S_)   // 16384

__device__ __forceinline__ u16 f2h(float f) {
  _Float16 h = (_Float16)f;
  return __builtin_bit_cast(u16, h);
}

// ---------- convert fp32 -> fp16 (W only) ----------
__global__ void f32_to_f16_kernel(const float* __restrict__ x,
                                  u16* __restrict__ o, int n4) {
  int stride = gridDim.x * blockDim.x;
  for (int i = blockIdx.x * blockDim.x + threadIdx.x; i < n4; i += stride) {
    float4 v = reinterpret_cast<const float4*>(x)[i];
    ushort4 h;
    h.x = f2h(v.x); h.y = f2h(v.y); h.z = f2h(v.z); h.w = f2h(v.w);
    reinterpret_cast<ushort4*>(o)[i] = h;
  }
}

// ---------- fused: X fp32 [b][s][h] -> XT fp16 [b][h][s] AND XF fp16 -------
__global__ __launch_bounds__(256) void transpose_f32_kernel(
    const float* __restrict__ x, u16* __restrict__ xt, u16* __restrict__ xf) {
  __shared__ u16 t[64][72];
  int b = blockIdx.z, s0 = blockIdx.x * 64, h0 = blockIdx.y * 64;
  int tid = threadIdx.x;
  int row = tid & 63, seg = tid >> 6;  // 4 segs x 16 elems
  const float* src = x + ((size_t)(b * S_ + s0 + row)) * H_ + h0 + seg * 16;
  u16* dstf = xf + ((size_t)(b * S_ + s0 + row)) * H_ + h0 + seg * 16;
#pragma unroll
  for (int j = 0; j < 4; ++j) {
    float4 v = reinterpret_cast<const float4*>(src)[j];
    ushort4 h;
    h.x = f2h(v.x); h.y = f2h(v.y); h.z = f2h(v.z); h.w = f2h(v.w);
    reinterpret_cast<ushort4*>(dstf)[j] = h;
    *reinterpret_cast<ushort4*>(&t[row][seg * 16 + j * 4]) = h;
  }
  __syncthreads();
  int hh = tid & 63, ss = tid >> 6;
  u16* dst = xt + ((size_t)(b * H_ + h0 + hh)) * S_ + s0 + ss * 16;
#pragma unroll
  for (int j = 0; j < 4; ++j) {
    ushort4 o;
    o.x = t[ss * 16 + j * 4 + 0][hh];
    o.y = t[ss * 16 + j * 4 + 1][hh];
    o.z = t[ss * 16 + j * 4 + 2][hh];
    o.w = t[ss * 16 + j * 4 + 3][hh];
    reinterpret_cast<ushort4*>(dst)[j] = o;
  }
}

// ---------- async global->LDS 16B ----------
__device__ __forceinline__ void async_stage16(const u16* g, u16* l) {
  __builtin_amdgcn_global_load_lds(
      (__attribute__((address_space(1))) void*)g,
      (__attribute__((address_space(3))) void*)l, 16, 0, 0);
}

// ---------- 256x256x64 4-phase fp16 BT-GEMM, 32x32x16 MFMA core ----------
// C[m,n] = sum_k A[m,k]*B[n,k]; 512 thr / 8 waves (2M x 4N); LDS 2 slots x
// (A+B half-tiles) = 128 KB; XOR-swizzle byte^((row&7)<<4) src + reads.
// r10: MFMA 32x32x16 (8.07cy/32KFLOP vs 2x4.85 for 16x16x32 = -17% matrix
// pipe, half the MFMA instructions). Per wave per quadrant-phase: 2 m-tiles
// x 1 n-tile x 4 ks = 8 MFMA. Schedule/ledger identical to r9 (verified):
// Gray q00->q01->q11->q10, one closing barrier/phase, stages into
// barrier-separated dead regions, single VM6 per tile after MFMA cluster.
template <int OM>  // 0: fp32 out; 1: fp16 out + bias
__global__ __launch_bounds__(512) void gemm8_kernel(
    const u16* __restrict__ A, const u16* __restrict__ B,
    float* __restrict__ Cf, u16* __restrict__ Ch,
    const float* __restrict__ bias,
    int lda, int ldb, int ldc, int K,
    long sAz, long sBz, long sCz) {
  __shared__ __align__(16) u16 sA[2][256 * 64];
  __shared__ __align__(16) u16 sB[2][256 * 64];

  // ---- XCD swizzle (T1, bijective m204) ----
  int gx = gridDim.x, gy = gridDim.y;
  int nwg = gx * gy * gridDim.z;
  int wgid = blockIdx.x + gx * (blockIdx.y + gy * blockIdx.z);
  int q = nwg >> 3, r = nwg & 7;
  int xcd = wgid & 7, idx = wgid >> 3;
  int nid = (xcd < r ? xcd * (q + 1) : r * (q + 1) + (xcd - r) * q) + idx;
  int bxi = nid % gx, t2 = nid / gx;
  int byi = t2 % gy, bzi = t2 / gy;

  int tid = threadIdx.x, wave = tid >> 6, lane = tid & 63;
  int wm = wave >> 2, wn = wave & 3;
  int bm = bxi * 256, bn = byi * 256;
  long zA = (long)bzi * sAz;
  long zB = (long)bzi * sBz;
  long zC = (long)bzi * sCz;
  const u16* gA = A + zA + (size_t)bm * lda;
  const u16* gB = B + zB + (size_t)bn * ldb;

  // staging constants
  int srow = tid >> 3;             // 0..63
  int scolb = (tid & 7) << 4;      // 0..112
  int sco = (scolb ^ ((srow & 7) << 4)) >> 1;
  size_t aO0 = (size_t)srow * lda + sco, aO1 = aO0 + (size_t)64 * lda;
  size_t bO0 = (size_t)srow * ldb + sco, bO1 = bO0 + (size_t)64 * ldb;
  int ld0 = srow * 64 + (scolb >> 1), ld1 = ld0 + 64 * 64;

  auto stgA = [&](int slot, int half, int kofs) {
    const u16* g = gA + (size_t)(half * 128) * lda + kofs;
    u16* l = &sA[slot][half * 8192];
    async_stage16(g + aO0, l + ld0);
    async_stage16(g + aO1, l + ld1);
  };
  auto stgB = [&](int slot, int half, int kofs) {
    const u16* g = gB + (size_t)(half * 128) * ldb + kofs;
    u16* l = &sB[slot][half * 8192];
    async_stage16(g + bO0, l + ld0);
    async_stage16(g + bO1, l + ld1);
  };

  // fragment reads (swizzled). 32x32x16 operand layout: lane holds
  // row/col = lane&31, k = (lane>>5)*8 + [0..8).
  int l31 = lane & 31;
  int kg32 = (lane >> 5) << 4;  // byte offset of lane's k-chunk
  auto frag = [&](const u16* base, int row, int colb) -> f16x8 {
    int off = (row << 7) + (colb ^ ((row & 7) << 4));
    return *reinterpret_cast<const f16x8*>(
        reinterpret_cast<const char*>(base) + off);
  };

  f16x8 aF[2][4];     // [mt][ks]
  f16x8 bF[2][4];     // [qn][ks] — both B halves resident
  f32x16 acc[4][2] = {};  // [qm*2+mt][qn]

  auto RA = [&](int slot, int qm) {
#pragma unroll
    for (int mt = 0; mt < 2; ++mt)
#pragma unroll
      for (int ks = 0; ks < 4; ++ks)
        aF[mt][ks] = frag(sA[slot], qm * 128 + wm * 64 + mt * 32 + l31,
                          ks * 32 + kg32);
  };
  auto RB = [&](int slot, int qn) {
#pragma unroll
    for (int ks = 0; ks < 4; ++ks)
      bF[qn][ks] = frag(sB[slot], qn * 128 + wn * 32 + l31, ks * 32 + kg32);
  };
  auto MM = [&](int qm, int qn) {
#pragma unroll
    for (int ks = 0; ks < 4; ++ks)
#pragma unroll
      for (int mt = 0; mt < 2; ++mt)
        acc[qm * 2 + mt][qn] = __builtin_amdgcn_mfma_f32_32x32x16_f16(
            aF[mt][ks], bF[qn][ks], acc[qm * 2 + mt][qn], 0, 0, 0);
  };

#define VM6 asm volatile("s_waitcnt vmcnt(6)" ::: "memory")
#define VM0 asm volatile("s_waitcnt vmcnt(0)" ::: "memory")
#define BAR __builtin_amdgcn_s_barrier()
#define LG0                                              \
  asm volatile("s_waitcnt lgkmcnt(0)" ::: "memory");     \
  __builtin_amdgcn_sched_barrier(0)
#define MFMA_CL(qm, qn)                 \
  __builtin_amdgcn_s_setprio(1);        \
  MM(qm, qn);                           \
  __builtin_amdgcn_s_setprio(0)

  int NT = K >> 6;  // K-tiles
  // prologue: T0 full -> slot0; T1's A0,B1,A1 -> slot1; VM6 retires T0.
  stgA(0, 0, 0); stgB(0, 0, 0); stgB(0, 1, 0); stgA(0, 1, 0);
  if (NT > 1) { stgA(1, 0, 64); stgB(1, 1, 64); stgA(1, 1, 64); }
  VM6;
  BAR;

  for (int t = 0; t < NT; ++t) {
    int s = t & 1, ns = s ^ 1;
    int k1 = (t + 1) << 6, k2 = (t + 2) << 6;
    bool p1 = (t + 1 < NT), p2 = (t + 2 < NT);
    // ph1 q00: read A0 + B0->bF0; stage B0(T+1)->ns (dead since ph1(t-1))
    RA(s, 0); RB(s, 0);
    if (p1) stgB(ns, 0, k1);
    LG0; MFMA_CL(0, 0); BAR;
    // ph2 q01: read B1->bF1 (keep aF); stage A0(T+2)->s (died ph1)
    RB(s, 1);
    if (p2) stgA(s, 0, k2);
    LG0; MFMA_CL(0, 1); BAR;
    // ph3 q11: read A1 (keep bF1); stage B1(T+2)->s (died ph2)
    RA(s, 1);
    if (p2) stgB(s, 1, k2);
    LG0; MFMA_CL(1, 1); BAR;
    // ph4 q10: NO reads (resident aF(q1)+bF0); stage A1(T+2)->s (died ph3)
    if (p2) stgA(s, 1, k2);
    MFMA_CL(1, 0);
    if (t < NT - 2) { VM6; } else if (t == NT - 2) { VM0; }
    BAR;
  }
#undef VM6
#undef VM0
#undef BAR
#undef LG0
#undef MFMA_CL

  // Epilogue. 32x32 C/D layout (m74/m101): col = lane&31,
  // row = (reg&3) + 8*(reg>>2) + 4*(lane>>5).
  int rsub = 4 * (lane >> 5);
#pragma unroll
  for (int mi = 0; mi < 4; ++mi) {
    int qm = mi >> 1, mt = mi & 1;
    int rowb = bm + qm * 128 + wm * 64 + mt * 32 + rsub;
#pragma unroll
    for (int ni = 0; ni < 2; ++ni) {
      int col = bn + ni * 128 + wn * 32 + l31;
#pragma unroll
      for (int reg = 0; reg < 16; ++reg) {
        int row = rowb + (reg & 3) + 8 * (reg >> 2);
        float v = acc[mi][ni][reg];
        if constexpr (OM == 1) {
          Ch[zC + (size_t)row * ldc + col] = f2h(v + bias[col]);
        } else {
          Cf[zC + (size_t)row * ldc + col] = v;
        }
      }
    }
  }
}

// ---------- row softmax: fp32 [rows][2048] -> fp16 (pitch opitch u16) -----
__global__ __launch_bounds__(256) void softmax_kernel(const float* __restrict__ sc,
                                                      u16* __restrict__ attn,
                                                      int opitch) {
  __shared__ float red[4];
  size_t row = blockIdx.x;
  const float* p = sc + row * S_;
  u16* o = attn + row * (size_t)opitch;
  int t = threadIdx.x;
  float4 v0 = reinterpret_cast<const float4*>(p)[t];
  float4 v1 = reinterpret_cast<const float4*>(p)[t + 256];
  float mx = fmaxf(fmaxf(fmaxf(v0.x, v0.y), fmaxf(v0.z, v0.w)),
                   fmaxf(fmaxf(v1.x, v1.y), fmaxf(v1.z, v1.w)));
#pragma unroll
  for (int d = 32; d > 0; d >>= 1) mx = fmaxf(mx, __shfl_xor(mx, d));
  if ((t & 63) == 0) red[t >> 6] = mx;
  __syncthreads();
  mx = fmaxf(fmaxf(red[0], red[1]), fmaxf(red[2], red[3]));
  float e[8];
  e[0] = __expf(v0.x - mx); e[1] = __expf(v0.y - mx);
  e[2] = __expf(v0.z - mx); e[3] = __expf(v0.w - mx);
  e[4] = __expf(v1.x - mx); e[5] = __expf(v1.y - mx);
  e[6] = __expf(v1.z - mx); e[7] = __expf(v1.w - mx);
  float s = ((e[0] + e[1]) + (e[2] + e[3])) + ((e[4] + e[5]) + (e[6] + e[7]));
#pragma unroll
  for (int d = 32; d > 0; d >>= 1) s += __shfl_xor(s, d);
  __syncthreads();
  if ((t & 63) == 0) red[t >> 6] = s;
  __syncthreads();
  s = (red[0] + red[1]) + (red[2] + red[3]);
  float inv = 1.0f / s;
  ushort4 h0, h1;
  h0.x = f2h(e[0] * inv); h0.y = f2h(e[1] * inv);
  h0.z = f2h(e[2] * inv); h0.w = f2h(e[3] * inv);
  h1.x = f2h(e[4] * inv); h1.y = f2h(e[5] * inv);
  h1.z = f2h(e[6] * inv); h1.w = f2h(e[7] * inv);
  // all reads happened before the syncthreads above -> in-place safe
  reinterpret_cast<ushort4*>(o)[t] = h0;
  reinterpret_cast<ushort4*>(o)[t + 256] = h1;
}

extern "C" void kernel_launch(void* const* d_in, const int* in_sizes, int n_in,
                              void* d_out, int out_size, void* d_ws, size_t ws_size,
                              hipStream_t stream) {
  const float* X = (const float*)d_in[0];     // [8,2048,1024] fp32
  const float* W = (const float*)d_in[1];     // [1024,1024] fp32 (out,in)
  const float* bias = (const float*)d_in[2];  // [1024] fp32
  float* out = (float*)d_out;
  char* ws = (char*)d_ws;

  const size_t MB = 1ull << 20;
  u16* XF = (u16*)(ws);               // 32MB [16384][1024] fp16
  u16* WF = (u16*)(ws + 32 * MB);     // 2MB
  u16* XT = (u16*)(ws + 34 * MB);     // 32MB [b][1024][2048] fp16
  u16* QW = (u16*)(ws + 66 * MB);     // 32MB [16384][1024] fp16
  float* SC = (float*)(ws + 98 * MB); // scores fp32 (full 128MB or CB*16MB)

  // plan A (ws>=226MB): full-batch score (512 blk) + 1 softmax + 1 PV.
  // plan B: CB=4 chunks, in-place P. Both overwrite SC with fp16 P.
  int CB = (ws_size >= 226 * MB) ? 8 : 4;
  int nch = B_ / CB;

  // 1) W -> fp16
  f32_to_f16_kernel<<<1024, 256, 0, stream>>>(W, WF, H_ * H_ / 4);
  // 2) fused: XF = fp16(X); XT[b][h][s] = fp16(X[b][s][h])
  transpose_f32_kernel<<<dim3(S_ / 64, H_ / 64, B_), 256, 0, stream>>>(
      X, XT, XF);
  // 3) QW = X @ W^T + b -> fp16
  gemm8_kernel<1><<<dim3(M_ / 256, H_ / 256, 1), 512, 0, stream>>>(
      XF, WF, nullptr, QW, bias, H_, H_, H_, H_, 0, 0, 0);
  // 4-6) per chunk: score -> softmax(in-place) -> PV
  for (int ch = 0; ch < nch; ++ch) {
    long off = (long)ch * CB;
    gemm8_kernel<0><<<dim3(S_ / 256, S_ / 256, CB), 512, 0, stream>>>(
        QW + off * S_ * H_, XF + off * S_ * H_, SC, nullptr, nullptr,
        H_, H_, S_, H_, (long)S_ * H_, (long)S_ * H_, (long)S_ * S_);
    softmax_kernel<<<CB * S_, 256, 0, stream>>>(SC, (u16*)SC, 2 * S_);
    gemm8_kernel<0><<<dim3(S_ / 256, H_ / 256, CB), 512, 0, stream>>>(
        (u16*)SC, XT + off * (long)H_ * S_,
        out + off * (long)S_ * H_, nullptr, nullptr,
        2 * S_, S_, H_, S_, (long)S_ * 2 * S_, (long)H_ * S_, (long)S_ * H_);
  }
}

// Round 11
// 257.532 us; speedup vs baseline: 1.0659x; 1.0659x over previous
//
#include <hip/hip_runtime.h>
#include <hip/hip_bf16.h>
#include <hip/hip_fp16.h>

typedef unsigned short u16;
typedef __attribute__((ext_vector_type(8))) _Float16 f16x8;  // 8 fp16 = 4 VGPR
typedef __attribute__((ext_vector_type(4))) float f32x4;     // MFMA 16x16 acc

#define B_ 8
#define S_ 2048
#define H_ 1024
#define M_ (B_ * S_)   // 16384

__device__ __forceinline__ u16 f2h(float f) {
  _Float16 h = (_Float16)f;
  return __builtin_bit_cast(u16, h);
}

// ---------- convert fp32 -> fp16 (W only) ----------
__global__ void f32_to_f16_kernel(const float* __restrict__ x,
                                  u16* __restrict__ o, int n4) {
  int stride = gridDim.x * blockDim.x;
  for (int i = blockIdx.x * blockDim.x + threadIdx.x; i < n4; i += stride) {
    float4 v = reinterpret_cast<const float4*>(x)[i];
    ushort4 h;
    h.x = f2h(v.x); h.y = f2h(v.y); h.z = f2h(v.z); h.w = f2h(v.w);
    reinterpret_cast<ushort4*>(o)[i] = h;
  }
}

// ---------- fused: X fp32 [b][s][h] -> XT fp16 [b][h][s] AND XF fp16 -------
__global__ __launch_bounds__(256) void transpose_f32_kernel(
    const float* __restrict__ x, u16* __restrict__ xt, u16* __restrict__ xf) {
  __shared__ u16 t[64][72];
  int b = blockIdx.z, s0 = blockIdx.x * 64, h0 = blockIdx.y * 64;
  int tid = threadIdx.x;
  int row = tid & 63, seg = tid >> 6;  // 4 segs x 16 elems
  const float* src = x + ((size_t)(b * S_ + s0 + row)) * H_ + h0 + seg * 16;
  u16* dstf = xf + ((size_t)(b * S_ + s0 + row)) * H_ + h0 + seg * 16;
#pragma unroll
  for (int j = 0; j < 4; ++j) {
    float4 v = reinterpret_cast<const float4*>(src)[j];
    ushort4 h;
    h.x = f2h(v.x); h.y = f2h(v.y); h.z = f2h(v.z); h.w = f2h(v.w);
    reinterpret_cast<ushort4*>(dstf)[j] = h;
    *reinterpret_cast<ushort4*>(&t[row][seg * 16 + j * 4]) = h;
  }
  __syncthreads();
  int hh = tid & 63, ss = tid >> 6;
  u16* dst = xt + ((size_t)(b * H_ + h0 + hh)) * S_ + s0 + ss * 16;
#pragma unroll
  for (int j = 0; j < 4; ++j) {
    ushort4 o;
    o.x = t[ss * 16 + j * 4 + 0][hh];
    o.y = t[ss * 16 + j * 4 + 1][hh];
    o.z = t[ss * 16 + j * 4 + 2][hh];
    o.w = t[ss * 16 + j * 4 + 3][hh];
    reinterpret_cast<ushort4*>(dst)[j] = o;
  }
}

// ---------- async global->LDS 16B ----------
__device__ __forceinline__ void async_stage16(const u16* g, u16* l) {
  __builtin_amdgcn_global_load_lds(
      (__attribute__((address_space(1))) void*)g,
      (__attribute__((address_space(3))) void*)l, 16, 0, 0);
}

// ---------- 256x256x64 4-phase fp16 BT-GEMM, pipelined fragment reads -----
// C[m,n] = sum_k A[m,k]*B[n,k]; 512 thr / 8 waves (2M x 4N); LDS 2 slots x
// (A+B half-tiles) = 128 KB; XOR-swizzle byte^((row&7)<<4) src + reads.
//
// r11: m201-style read-ahead. Dual fragment sets; phase p issues the reads
// needed by phase p+1, so the compiler's COUNTED lgkmcnt (no manual drain,
// no sched_barrier) lets each phase's LDS latency hide under the previous
// MFMA cluster. Only q00's reads (12/tile) are latency-exposed at loop top
// (their regions become safe only after VM6+BAR).
// Stage/death ledger identical to r8/r9 (proven): stages target regions
// whose last reads were CONSUMED (compiler wait precedes that phase's MFMA,
// which precedes its closing barrier) at least one barrier earlier:
//   ph1: B0(T+1)->ns [B0(ns) read consumed ph1(t-1)]
//   ph2: A0(T+2)->s  [A0 reads issued ph0(t), consumed ph1(t)]
//   ph3: B1(T+2)->s  [B1 reads issued ph1(t), consumed ph2(t)]
//   ph4: A1(T+2)->s  [A1 reads issued ph2(t), consumed ph3(t)]
// vmcnt FIFO: entering tile: 6 outstanding {A0,B1,A1}(T+1); +2 per phase ->
// 14 at ph4; VM6 retires exactly T+1's four halves. VM6 is a volatile-asm
// fence immediately before the closing barrier -> next tile's reads cannot
// hoist above the retirement point. Tail: VM0 at NT-2.
template <int OM>  // 0: fp32 out; 1: fp16 out + bias
__global__ __launch_bounds__(512) void gemm8_kernel(
    const u16* __restrict__ A, const u16* __restrict__ B,
    float* __restrict__ Cf, u16* __restrict__ Ch,
    const float* __restrict__ bias,
    int lda, int ldb, int ldc, int K,
    long sAz, long sBz, long sCz) {
  __shared__ __align__(16) u16 sA[2][256 * 64];
  __shared__ __align__(16) u16 sB[2][256 * 64];

  // ---- XCD swizzle (T1, bijective m204) ----
  int gx = gridDim.x, gy = gridDim.y;
  int nwg = gx * gy * gridDim.z;
  int wgid = blockIdx.x + gx * (blockIdx.y + gy * blockIdx.z);
  int q = nwg >> 3, r = nwg & 7;
  int xcd = wgid & 7, idx = wgid >> 3;
  int nid = (xcd < r ? xcd * (q + 1) : r * (q + 1) + (xcd - r) * q) + idx;
  int bxi = nid % gx, t2 = nid / gx;
  int byi = t2 % gy, bzi = t2 / gy;

  int tid = threadIdx.x, wave = tid >> 6, lane = tid & 63;
  int wm = wave >> 2, wn = wave & 3;
  int bm = bxi * 256, bn = byi * 256;
  long zA = (long)bzi * sAz;
  long zB = (long)bzi * sBz;
  long zC = (long)bzi * sCz;
  const u16* gA = A + zA + (size_t)bm * lda;
  const u16* gB = B + zB + (size_t)bn * ldb;

  // staging constants: thread -> (row srow/srow+64, byte col scolb) of a half
  int srow = tid >> 3;             // 0..63
  int scolb = (tid & 7) << 4;      // 0..112
  int sco = (scolb ^ ((srow & 7) << 4)) >> 1;  // swizzled src col (u16)
  size_t aO0 = (size_t)srow * lda + sco, aO1 = aO0 + (size_t)64 * lda;
  size_t bO0 = (size_t)srow * ldb + sco, bO1 = bO0 + (size_t)64 * ldb;
  int ld0 = srow * 64 + (scolb >> 1), ld1 = ld0 + 64 * 64;

  auto stgA = [&](int slot, int half, int kofs) {
    const u16* g = gA + (size_t)(half * 128) * lda + kofs;
    u16* l = &sA[slot][half * 8192];
    async_stage16(g + aO0, l + ld0);
    async_stage16(g + aO1, l + ld1);
  };
  auto stgB = [&](int slot, int half, int kofs) {
    const u16* g = gB + (size_t)(half * 128) * ldb + kofs;
    u16* l = &sB[slot][half * 8192];
    async_stage16(g + bO0, l + ld0);
    async_stage16(g + bO1, l + ld1);
  };

  // fragment reads (swizzled)
  int la = lane & 15;
  int kg = (lane >> 4) << 4;
  auto frag = [&](const u16* base, int row, int colb) -> f16x8 {
    int off = (row << 7) + (colb ^ ((row & 7) << 4));
    return *reinterpret_cast<const f16x8*>(
        reinterpret_cast<const char*>(base) + off);
  };

  // dual fragment sets (read-ahead pipeline)
  f16x8 aF0[4][2], aF1[4][2];  // A half 0 / half 1
  f16x8 bF0[2][2], bF1[2][2];  // B half 0 / half 1
  f32x4 acc[8][4] = {};

  auto RA = [&](int slot, int qm, f16x8(&dst)[4][2]) {
#pragma unroll
    for (int j = 0; j < 4; ++j)
#pragma unroll
      for (int ks = 0; ks < 2; ++ks)
        dst[j][ks] = frag(sA[slot], qm * 128 + (j * 2 + wm) * 16 + la,
                          ks * 64 + kg);
  };
  auto RB = [&](int slot, int qn, f16x8(&dst)[2][2]) {
#pragma unroll
    for (int i = 0; i < 2; ++i)
#pragma unroll
      for (int ks = 0; ks < 2; ++ks)
        dst[i][ks] = frag(sB[slot], qn * 128 + (i * 4 + wn) * 16 + la,
                          ks * 64 + kg);
  };
  auto MM = [&](int qm, int qn, f16x8(&a)[4][2], f16x8(&b)[2][2]) {
#pragma unroll
    for (int ks = 0; ks < 2; ++ks)
#pragma unroll
      for (int j = 0; j < 4; ++j)
#pragma unroll
        for (int i = 0; i < 2; ++i)
          acc[qm * 4 + j][qn * 2 + i] = __builtin_amdgcn_mfma_f32_16x16x32_f16(
              a[j][ks], b[i][ks], acc[qm * 4 + j][qn * 2 + i], 0, 0, 0);
  };

#define VM6 asm volatile("s_waitcnt vmcnt(6)" ::: "memory")
#define VM0 asm volatile("s_waitcnt vmcnt(0)" ::: "memory")
#define BAR __builtin_amdgcn_s_barrier()
#define PRIO1 __builtin_amdgcn_s_setprio(1)
#define PRIO0 __builtin_amdgcn_s_setprio(0)

  int NT = K >> 6;  // K-tiles
  // prologue: T0 (A0,B0,B1,A1) -> slot0; T1's A0,B1,A1 -> slot1.
  // VM6 retires all 8 loads of T0, keeps T1's 6 -> steady-state FIFO.
  stgA(0, 0, 0); stgB(0, 0, 0); stgB(0, 1, 0); stgA(0, 1, 0);
  if (NT > 1) { stgA(1, 0, 64); stgB(1, 1, 64); stgA(1, 1, 64); }
  VM6;
  BAR;

  for (int t = 0; t < NT; ++t) {
    int s = t & 1, ns = s ^ 1;
    int k1 = (t + 1) << 6, k2 = (t + 2) << 6;
    bool p1 = (t + 1 < NT), p2 = (t + 2 < NT);
    // ph1: read q00 frags (exposed) + read-ahead bF1; stage B0(T+1)->ns
    RA(s, 0, aF0); RB(s, 0, bF0);
    RB(s, 1, bF1);
    if (p1) stgB(ns, 0, k1);
    PRIO1; MM(0, 0, aF0, bF0); PRIO0; BAR;
    // ph2: read-ahead aF1; stage A0(T+2)->s (died ph1); MFMA q01
    RA(s, 1, aF1);
    if (p2) stgA(s, 0, k2);
    PRIO1; MM(0, 1, aF0, bF1); PRIO0; BAR;
    // ph3: stage B1(T+2)->s (died ph2); MFMA q11
    if (p2) stgB(s, 1, k2);
    PRIO1; MM(1, 1, aF1, bF1); PRIO0; BAR;
    // ph4: stage A1(T+2)->s (died ph3); MFMA q10 (resident frags); VM; BAR
    if (p2) stgA(s, 1, k2);
    PRIO1; MM(1, 0, aF1, bF0); PRIO0;
    if (t < NT - 2) { VM6; } else if (t == NT - 2) { VM0; }
    BAR;
  }
#undef VM6
#undef VM0
#undef BAR
#undef PRIO1
#undef PRIO0

  // Epilogue. C/D layout (16x16): col = lane&15, row = (lane>>4)*4 + reg.
#pragma unroll
  for (int mf = 0; mf < 8; ++mf) {
    int qm = mf >> 2, j = mf & 3;
    int row = bm + qm * 128 + (j * 2 + wm) * 16 + (lane >> 4) * 4;
#pragma unroll
    for (int nf = 0; nf < 4; ++nf) {
      int qn = nf >> 1, i = nf & 1;
      int col = bn + qn * 128 + (i * 4 + wn) * 16 + la;
#pragma unroll
      for (int r = 0; r < 4; ++r) {
        float v = acc[mf][nf][r];
        if constexpr (OM == 1) {
          Ch[zC + (size_t)(row + r) * ldc + col] = f2h(v + bias[col]);
        } else {
          Cf[zC + (size_t)(row + r) * ldc + col] = v;
        }
      }
    }
  }
}

// ---------- row softmax: fp32 [rows][2048] -> fp16 (pitch opitch u16) -----
__global__ __launch_bounds__(256) void softmax_kernel(const float* __restrict__ sc,
                                                      u16* __restrict__ attn,
                                                      int opitch) {
  __shared__ float red[4];
  size_t row = blockIdx.x;
  const float* p = sc + row * S_;
  u16* o = attn + row * (size_t)opitch;
  int t = threadIdx.x;
  float4 v0 = reinterpret_cast<const float4*>(p)[t];
  float4 v1 = reinterpret_cast<const float4*>(p)[t + 256];
  float mx = fmaxf(fmaxf(fmaxf(v0.x, v0.y), fmaxf(v0.z, v0.w)),
                   fmaxf(fmaxf(v1.x, v1.y), fmaxf(v1.z, v1.w)));
#pragma unroll
  for (int d = 32; d > 0; d >>= 1) mx = fmaxf(mx, __shfl_xor(mx, d));
  if ((t & 63) == 0) red[t >> 6] = mx;
  __syncthreads();
  mx = fmaxf(fmaxf(red[0], red[1]), fmaxf(red[2], red[3]));
  float e[8];
  e[0] = __expf(v0.x - mx); e[1] = __expf(v0.y - mx);
  e[2] = __expf(v0.z - mx); e[3] = __expf(v0.w - mx);
  e[4] = __expf(v1.x - mx); e[5] = __expf(v1.y - mx);
  e[6] = __expf(v1.z - mx); e[7] = __expf(v1.w - mx);
  float s = ((e[0] + e[1]) + (e[2] + e[3])) + ((e[4] + e[5]) + (e[6] + e[7]));
#pragma unroll
  for (int d = 32; d > 0; d >>= 1) s += __shfl_xor(s, d);
  __syncthreads();
  if ((t & 63) == 0) red[t >> 6] = s;
  __syncthreads();
  s = (red[0] + red[1]) + (red[2] + red[3]);
  float inv = 1.0f / s;
  ushort4 h0, h1;
  h0.x = f2h(e[0] * inv); h0.y = f2h(e[1] * inv);
  h0.z = f2h(e[2] * inv); h0.w = f2h(e[3] * inv);
  h1.x = f2h(e[4] * inv); h1.y = f2h(e[5] * inv);
  h1.z = f2h(e[6] * inv); h1.w = f2h(e[7] * inv);
  // all reads happened before the syncthreads above -> in-place safe
  reinterpret_cast<ushort4*>(o)[t] = h0;
  reinterpret_cast<ushort4*>(o)[t + 256] = h1;
}

extern "C" void kernel_launch(void* const* d_in, const int* in_sizes, int n_in,
                              void* d_out, int out_size, void* d_ws, size_t ws_size,
                              hipStream_t stream) {
  const float* X = (const float*)d_in[0];     // [8,2048,1024] fp32
  const float* W = (const float*)d_in[1];     // [1024,1024] fp32 (out,in)
  const float* bias = (const float*)d_in[2];  // [1024] fp32
  float* out = (float*)d_out;
  char* ws = (char*)d_ws;

  const size_t MB = 1ull << 20;
  u16* XF = (u16*)(ws);               // 32MB [16384][1024] fp16
  u16* WF = (u16*)(ws + 32 * MB);     // 2MB
  u16* XT = (u16*)(ws + 34 * MB);     // 32MB [b][1024][2048] fp16
  u16* QW = (u16*)(ws + 66 * MB);     // 32MB [16384][1024] fp16
  float* SC = (float*)(ws + 98 * MB); // scores fp32 (full 128MB or CB*16MB)

  // plan A (ws>=226MB): full-batch score (512 blk) + 1 softmax + 1 PV.
  // plan B: CB=4 chunks, in-place P. Both overwrite SC with fp16 P.
  int CB = (ws_size >= 226 * MB) ? 8 : 4;
  int nch = B_ / CB;

  // 1) W -> fp16
  f32_to_f16_kernel<<<1024, 256, 0, stream>>>(W, WF, H_ * H_ / 4);
  // 2) fused: XF = fp16(X); XT[b][h][s] = fp16(X[b][s][h])
  transpose_f32_kernel<<<dim3(S_ / 64, H_ / 64, B_), 256, 0, stream>>>(
      X, XT, XF);
  // 3) QW = X @ W^T + b -> fp16
  gemm8_kernel<1><<<dim3(M_ / 256, H_ / 256, 1), 512, 0, stream>>>(
      XF, WF, nullptr, QW, bias, H_, H_, H_, H_, 0, 0, 0);
  // 4-6) per chunk: score -> softmax(in-place) -> PV
  for (int ch = 0; ch < nch; ++ch) {
    long off = (long)ch * CB;
    gemm8_kernel<0><<<dim3(S_ / 256, S_ / 256, CB), 512, 0, stream>>>(
        QW + off * S_ * H_, XF + off * S_ * H_, SC, nullptr, nullptr,
        H_, H_, S_, H_, (long)S_ * H_, (long)S_ * H_, (long)S_ * S_);
    softmax_kernel<<<CB * S_, 256, 0, stream>>>(SC, (u16*)SC, 2 * S_);
    gemm8_kernel<0><<<dim3(S_ / 256, H_ / 256, CB), 512, 0, stream>>>(
        (u16*)SC, XT + off * (long)H_ * S_,
        out + off * (long)S_ * H_, nullptr, nullptr,
        2 * S_, S_, H_, S_, (long)S_ * 2 * S_, (long)H_ * S_, (long)S_ * H_);
  }
}